// Round 1
// baseline (605.893 us; speedup 1.0000x reference)
//
#include <hip/hip_runtime.h>
#include <math.h>

// Problem constants (from reference)
#define R_ 5
#define NN 68      // N_NODES == LATENT
#define KK 32      // neighbors per node
#define NL 3       // GCN layers
#define LAT 68

// v1: correctness-first baseline.
// One batch element per block (grid = B). 128 threads (2 waves); threads
// t < 68 own node t for the compute phases; outer product is row-per-thread
// (row i = t) with float4 LDS reads (wave-uniform address -> broadcast) and
// float4 coalesced global stores.
__global__ __launch_bounds__(128) void gcn_fused(
    const float* __restrict__ z, const int* __restrict__ adj,
    const float* __restrict__ fc_w, const float* __restrict__ fc_b,
    const float* __restrict__ gw, const float* __restrict__ gb,
    float* __restrict__ out, int batch_total) {
  const int b = blockIdx.x;
  if (b >= batch_total) return;
  const int t = threadIdx.x;
  const bool active = (t < NN);

  // xs: ping-pong layer activations; X: final x per channel r (row stride 68
  // floats = 272 B, 16B-multiple -> float4-aligned reads of X[r][j], j%4==0).
  __shared__ float xs[2][NN];
  __shared__ float X[R_][NN];

  // Hoist adjacency row into registers (static unroll -> stays in VGPRs).
  int adjv[KK];
  if (active) {
#pragma unroll
    for (int k = 0; k < KK; ++k) adjv[k] = adj[t * KK + k];
  }

  const float* zb = z + (size_t)b * LAT;  // wave-uniform base -> scalar loads

  for (int r = 0; r < R_; ++r) {
    // ---- phase 1: x0 = z @ fc_w[r] + fc_b[r]  (no activation) ----
    if (active) {
      float v = fc_b[r * NN + t];
#pragma unroll 4
      for (int l = 0; l < LAT; ++l) {
        // zb[l]: uniform across lanes (broadcast / s_load);
        // fc_w[(r*68+l)*68 + t]: lanes contiguous in t -> coalesced.
        v = fmaf(zb[l], fc_w[(size_t)(r * LAT + l) * NN + t], v);
      }
      xs[0][t] = v;
    }
    __syncthreads();

    // ---- phase 2: 3 GCN layers with LDS gather ----
    int cur = 0;
    for (int l = 0; l < NL; ++l) {
      float v = 0.0f;
      if (active) {
        v = gb[(size_t)(r * NL + l) * NN + t];
        const float* wrow = gw + ((size_t)(r * NL + l) * NN + t) * KK;
#pragma unroll
        for (int k = 0; k < KK; ++k) {
          v = fmaf(xs[cur][adjv[k]], wrow[k], v);
        }
        v = 1.0f / (1.0f + __expf(-v));
      }
      // writes go to the other buffer; one barrier after the write makes it
      // visible for the next layer's gathers.
      if (active) xs[1 - cur][t] = v;
      __syncthreads();
      cur = 1 - cur;
    }
    if (active) X[r][t] = xs[cur][t];
    __syncthreads();  // X[r] visible before next r reuses xs / before phase 3
  }

  // ---- phase 3: out[b][i][j] = sum_r X[r][i] * X[r][j] ----
  // (outer product is already symmetric; 0.5*(S+S^T) is a no-op)
  float* ob = out + (size_t)b * (NN * NN);
  if (active) {
    float xi[R_];
#pragma unroll
    for (int r = 0; r < R_; ++r) xi[r] = X[r][t];
    const int i = t;
#pragma unroll 1
    for (int j = 0; j < NN; j += 4) {
      float4 acc = make_float4(0.f, 0.f, 0.f, 0.f);
#pragma unroll
      for (int r = 0; r < R_; ++r) {
        const float4 xj = *reinterpret_cast<const float4*>(&X[r][j]);
        acc.x = fmaf(xi[r], xj.x, acc.x);
        acc.y = fmaf(xi[r], xj.y, acc.y);
        acc.z = fmaf(xi[r], xj.z, acc.z);
        acc.w = fmaf(xi[r], xj.w, acc.w);
      }
      *reinterpret_cast<float4*>(&ob[(size_t)i * NN + j]) = acc;
    }
  }
}

extern "C" void kernel_launch(void* const* d_in, const int* in_sizes, int n_in,
                              void* d_out, int out_size, void* d_ws, size_t ws_size,
                              hipStream_t stream) {
  const float* z    = (const float*)d_in[0];  // (16384, 68)
  const int*   adj  = (const int*)  d_in[1];  // (68, 32)
  const float* fc_w = (const float*)d_in[2];  // (5, 68, 68)
  const float* fc_b = (const float*)d_in[3];  // (5, 68)
  const float* gw   = (const float*)d_in[4];  // (5, 3, 68, 32)
  const float* gb   = (const float*)d_in[5];  // (5, 3, 68)
  float* out = (float*)d_out;                 // (16384, 4624)

  const int batch = in_sizes[0] / LAT;        // 16384

  gcn_fused<<<batch, 128, 0, stream>>>(z, adj, fc_w, fc_b, gw, gb, out, batch);
}

// Round 2
// 350.381 us; speedup vs baseline: 1.7292x; 1.7292x over previous
//
#include <hip/hip_runtime.h>
#include <math.h>

// Problem constants (from reference)
#define R_ 5
#define NN 68      // N_NODES == LATENT
#define KK 32      // neighbors per node
#define NL 3       // GCN layers
#define LAT 68
#define NACT (R_ * NN)     // 340 active compute threads (r-parallel)
#define TPB 384            // 6 waves
#define NF4 ((NN * NN) / 4)  // 1156 float4 per output row
#define ROWF4 (NN / 4)       // 17 float4 per node row (exact)

// v2: one batch per block; r-channels parallel across threads; flat
// coalesced float4 stores for the outer product.
__global__ __launch_bounds__(TPB) void gcn_fused2(
    const float* __restrict__ z, const int* __restrict__ adj,
    const float* __restrict__ fc_w, const float* __restrict__ fc_b,
    const float* __restrict__ gw, const float* __restrict__ gb,
    float* __restrict__ out) {
  const int b = blockIdx.x;
  const int t = threadIdx.x;

  __shared__ float zs[LAT];            // this batch's z vector
  __shared__ int   adjs[NN][KK + 1];   // +1 pad: unpadded -> 32-way bank conflict
  __shared__ float xs[2][R_][NN];      // ping-pong activations, all 5 channels

  // ---- stage z (68 floats) and adjacency (68x32 ints), coalesced ----
  if (t < LAT) zs[t] = z[(size_t)b * LAT + t];
  for (int idx = t; idx < NN * KK; idx += TPB) {
    const int n = idx >> 5;            // /KK
    const int k = idx & (KK - 1);      // %KK
    adjs[n][k] = adj[idx];
  }
  __syncthreads();

  const int rr = t / NN;               // channel 0..4 (t < NACT)
  const int n  = t - rr * NN;          // node 0..67
  const bool active = (t < NACT);

  // adjacency row -> registers (LDS reads, conflict-free via pad)
  int adjv[KK];
  if (active) {
#pragma unroll
    for (int k = 0; k < KK; ++k) adjv[k] = adjs[n][k];
  }

  // ---- fc: x0 = z @ fc_w[rr] + fc_b[rr] (no activation) ----
  if (active) {
    float v = fc_b[rr * NN + n];
#pragma unroll 4
    for (int l = 0; l < LAT; ++l) {
      // zs[l]: uniform -> LDS broadcast; fc_w: lanes (rr,n) -> coalesced runs
      v = fmaf(zs[l], fc_w[(size_t)(rr * LAT + l) * NN + n], v);
    }
    xs[0][rr][n] = v;
  }
  __syncthreads();

  // ---- 3 GCN layers: gather from xs[cur], write xs[1-cur] ----
  int cur = 0;
#pragma unroll
  for (int l = 0; l < NL; ++l) {
    if (active) {
      float v = gb[(size_t)(rr * NL + l) * NN + n];
      const float4* wrow = reinterpret_cast<const float4*>(
          gw + ((size_t)(rr * NL + l) * NN + n) * KK);
      const float* xc = &xs[cur][rr][0];
#pragma unroll
      for (int kk = 0; kk < KK / 4; ++kk) {
        const float4 w4 = wrow[kk];     // 16B per lane (4x fewer scattered loads)
        v = fmaf(xc[adjv[4 * kk + 0]], w4.x, v);
        v = fmaf(xc[adjv[4 * kk + 1]], w4.y, v);
        v = fmaf(xc[adjv[4 * kk + 2]], w4.z, v);
        v = fmaf(xc[adjv[4 * kk + 3]], w4.w, v);
      }
      v = 1.0f / (1.0f + __expf(-v));
      xs[1 - cur][rr][n] = v;
    }
    __syncthreads();
    cur = 1 - cur;
  }
  // NL=3 odd -> final activations in xs[1] (== xs[cur])

  // ---- outer product, flat & coalesced ----
  // out[b][i][j] = sum_r X[r][i] * X[r][j]; symmetric so 0.5*(S+S^T) is a no-op.
  const float* Xs = &xs[cur][0][0];     // [R_][NN] contiguous, 16B-aligned
  float4* ob4 = reinterpret_cast<float4*>(out + (size_t)b * (NN * NN));
#pragma unroll 1
  for (int f = t; f < NF4; f += TPB) {
    const int i = f / ROWF4;            // row 0..67 (magic-mul)
    const int q = f - i * ROWF4;        // float4 col 0..16 (never crosses rows)
    float4 acc = make_float4(0.f, 0.f, 0.f, 0.f);
#pragma unroll
    for (int r = 0; r < R_; ++r) {
      const float xi = Xs[r * NN + i];
      const float4 xj = *reinterpret_cast<const float4*>(&Xs[r * NN + 4 * q]);
      acc.x = fmaf(xi, xj.x, acc.x);
      acc.y = fmaf(xi, xj.y, acc.y);
      acc.z = fmaf(xi, xj.z, acc.z);
      acc.w = fmaf(xi, xj.w, acc.w);
    }
    ob4[f] = acc;                       // lanes consecutive -> 1KB/instr coalesced
  }
}

extern "C" void kernel_launch(void* const* d_in, const int* in_sizes, int n_in,
                              void* d_out, int out_size, void* d_ws, size_t ws_size,
                              hipStream_t stream) {
  const float* z    = (const float*)d_in[0];  // (16384, 68)
  const int*   adj  = (const int*)  d_in[1];  // (68, 32)
  const float* fc_w = (const float*)d_in[2];  // (5, 68, 68)
  const float* fc_b = (const float*)d_in[3];  // (5, 68)
  const float* gw   = (const float*)d_in[4];  // (5, 3, 68, 32)
  const float* gb   = (const float*)d_in[5];  // (5, 3, 68)
  float* out = (float*)d_out;                 // (16384, 4624)

  const int batch = in_sizes[0] / LAT;        // 16384

  gcn_fused2<<<batch, TPB, 0, stream>>>(z, adj, fc_w, fc_b, gw, gb, out);
}

// Round 3
// 238.535 us; speedup vs baseline: 2.5401x; 1.4689x over previous
//
#include <hip/hip_runtime.h>
#include <math.h>

// Problem constants
#define R_ 5
#define NN 68      // N_NODES == LATENT
#define KK 32      // neighbors per node
#define NL 3       // GCN layers
#define LAT 68
#define BB 64              // batches per block (lane = batch)
#define TPB (R_ * 64)      // 320 threads = 5 waves (wave = channel r)
#define NF4 ((NN * NN) / 4)  // 1156 float4 per output row
#define ROWQ (NN / 4)        // 17 float4 per node row
#define XSTRIDE (NN * BB)    // 4352 floats per r-slab in LDS

// ---------------- prep: densify GCN weights ----------------
// W'[m][n] = sum_{k: adj[n,k]==m} gw[n,k]  (exact rewrite of the gather)
__global__ __launch_bounds__(128) void densify_k(
    const int* __restrict__ adj, const float* __restrict__ gw,
    float* __restrict__ wd) {
  const int rl = blockIdx.x;  // r*NL + l in 0..14
  const int t = threadIdx.x;
  __shared__ float col[NN][NN + 4];  // [m][n], padded
  for (int i = t; i < NN * (NN + 4); i += 128) (&col[0][0])[i] = 0.0f;
  __syncthreads();
  if (t < NN) {
    const int n = t;  // thread owns column n -> no races
    const int* ar = adj + n * KK;
    const float* wr = gw + ((size_t)rl * NN + n) * KK;
    for (int k = 0; k < KK; ++k) col[ar[k]][n] += wr[k];
  }
  __syncthreads();
  float* wout = wd + (size_t)rl * NN * NN;  // [m][n], n contiguous
  for (int i = t; i < NN * NN; i += 128) {
    const int m = i / NN, n = i - m * NN;
    wout[i] = col[m][n];
  }
}

// ---------------- main: fused GEMM-chain + outer product ----------------
// grid = B/64 = 256 blocks (1/CU). Wave w computes channel r=w for the
// block's 64 batches (lane = batch). x lives in LDS as [n][lane]: each lane
// touches only its own column -> no intra-phase barriers needed. Weights are
// wave-uniform b128 loads from L2. Final X written transposed [lane][n];
// store phase is flat-coalesced float4 over the 64x1156 output tile.
__global__ __launch_bounds__(TPB) void gcn_main_k(
    const float* __restrict__ z, const float* __restrict__ fc_w,
    const float* __restrict__ fc_b, const float* __restrict__ wd,
    const float* __restrict__ gb, float* __restrict__ out) {
  const int t = threadIdx.x;
  const int r = t >> 6;      // wave id = channel
  const int lane = t & 63;   // batch within block
  const int b0 = blockIdx.x * BB;

  __shared__ float zs[LAT][BB];      // z transposed: [l][b]   (17.4 KB)
  __shared__ float xs[R_][XSTRIDE];  // per-r x: [n][lane] then [lane][n] (85 KB)

  // stage z transposed (coalesced global reads)
  for (int idx = t; idx < BB * LAT; idx += TPB) {
    const int bb = idx / LAT;
    const int l = idx - bb * LAT;
    zs[l][bb] = z[(size_t)(b0 + bb) * LAT + l];
  }
  __syncthreads();

  float4 acc[ROWQ];  // 68 accumulators, statically indexed

  // ---- fc: x0 = z @ fc_w[r] + fc_b[r] (no activation) ----
  {
    const float4* bi = reinterpret_cast<const float4*>(fc_b + r * NN);
#pragma unroll
    for (int j = 0; j < ROWQ; ++j) acc[j] = bi[j];
    const float* wb = fc_w + (size_t)r * LAT * NN;  // [m][n], n contiguous
#pragma unroll 2
    for (int m = 0; m < LAT; ++m) {
      const float xm = zs[m][lane];  // stride-64 -> conflict-free
      const float4* w4 = reinterpret_cast<const float4*>(wb + m * NN);
#pragma unroll
      for (int j = 0; j < ROWQ; ++j) {
        const float4 ww = w4[j];  // wave-uniform -> scalar/broadcast
        acc[j].x = fmaf(xm, ww.x, acc[j].x);
        acc[j].y = fmaf(xm, ww.y, acc[j].y);
        acc[j].z = fmaf(xm, ww.z, acc[j].z);
        acc[j].w = fmaf(xm, ww.w, acc[j].w);
      }
    }
    float* xw = &xs[r][0];
#pragma unroll
    for (int j = 0; j < ROWQ; ++j) {  // write column lane (lane-private)
      xw[(4 * j + 0) * BB + lane] = acc[j].x;
      xw[(4 * j + 1) * BB + lane] = acc[j].y;
      xw[(4 * j + 2) * BB + lane] = acc[j].z;
      xw[(4 * j + 3) * BB + lane] = acc[j].w;
    }
  }

  // ---- 3 GCN layers: x = sigmoid(x @ W'[r,l] + b) ----
  for (int l = 0; l < NL; ++l) {
    const float4* bi = reinterpret_cast<const float4*>(gb + (r * NL + l) * NN);
#pragma unroll
    for (int j = 0; j < ROWQ; ++j) acc[j] = bi[j];
    const float* wb = wd + (size_t)(r * NL + l) * NN * NN;
    const float* xr = &xs[r][0];
#pragma unroll 2
    for (int m = 0; m < NN; ++m) {
      const float xm = xr[m * BB + lane];  // own column, conflict-free
      const float4* w4 = reinterpret_cast<const float4*>(wb + m * NN);
#pragma unroll
      for (int j = 0; j < ROWQ; ++j) {
        const float4 ww = w4[j];
        acc[j].x = fmaf(xm, ww.x, acc[j].x);
        acc[j].y = fmaf(xm, ww.y, acc[j].y);
        acc[j].z = fmaf(xm, ww.z, acc[j].z);
        acc[j].w = fmaf(xm, ww.w, acc[j].w);
      }
    }
#pragma unroll
    for (int j = 0; j < ROWQ; ++j) {  // sigmoid
      acc[j].x = 1.0f / (1.0f + __expf(-acc[j].x));
      acc[j].y = 1.0f / (1.0f + __expf(-acc[j].y));
      acc[j].z = 1.0f / (1.0f + __expf(-acc[j].z));
      acc[j].w = 1.0f / (1.0f + __expf(-acc[j].w));
    }
    if (l == NL - 1) {
      // final layer: write TRANSPOSED [lane][n] for the store phase (b128)
      float4* xt4 = reinterpret_cast<float4*>(&xs[r][lane * NN]);
#pragma unroll
      for (int j = 0; j < ROWQ; ++j) xt4[j] = acc[j];
    } else {
      float* xw = &xs[r][0];
#pragma unroll
      for (int j = 0; j < ROWQ; ++j) {
        xw[(4 * j + 0) * BB + lane] = acc[j].x;
        xw[(4 * j + 1) * BB + lane] = acc[j].y;
        xw[(4 * j + 2) * BB + lane] = acc[j].z;
        xw[(4 * j + 3) * BB + lane] = acc[j].w;
      }
    }
  }
  __syncthreads();  // X for all 5 r now visible block-wide

  // ---- outer product + flat coalesced store ----
  // out[b][i][j] = sum_r X[r][b][i] * X[r][b][j]; symmetric -> 0.5(S+S^T) no-op
  const float* X = &xs[0][0];
  float4* ob = reinterpret_cast<float4*>(out) + (size_t)b0 * NF4;
  const int total = BB * NF4;  // 73984
  for (int fg = t; fg < total; fg += TPB) {
    const int bb = fg / NF4;
    const int f = fg - bb * NF4;
    const int i = f / ROWQ;
    const int q = f - i * ROWQ;
    float4 a = make_float4(0.f, 0.f, 0.f, 0.f);
#pragma unroll
    for (int rr = 0; rr < R_; ++rr) {
      const float xi = X[rr * XSTRIDE + bb * NN + i];
      const float4 xj =
          *reinterpret_cast<const float4*>(X + rr * XSTRIDE + bb * NN + 4 * q);
      a.x = fmaf(xi, xj.x, a.x);
      a.y = fmaf(xi, xj.y, a.y);
      a.z = fmaf(xi, xj.z, a.z);
      a.w = fmaf(xi, xj.w, a.w);
    }
    ob[fg] = a;  // lanes consecutive -> fully coalesced
  }
}

extern "C" void kernel_launch(void* const* d_in, const int* in_sizes, int n_in,
                              void* d_out, int out_size, void* d_ws, size_t ws_size,
                              hipStream_t stream) {
  const float* z    = (const float*)d_in[0];  // (16384, 68)
  const int*   adj  = (const int*)  d_in[1];  // (68, 32)
  const float* fc_w = (const float*)d_in[2];  // (5, 68, 68)
  const float* fc_b = (const float*)d_in[3];  // (5, 68)
  const float* gw   = (const float*)d_in[4];  // (5, 3, 68, 32)
  const float* gb   = (const float*)d_in[5];  // (5, 3, 68)
  float* out = (float*)d_out;                 // (16384, 4624)
  float* wd  = (float*)d_ws;                  // densified W': 15*68*68 f32 = 277 KB

  const int B = in_sizes[0] / LAT;            // 16384

  densify_k<<<R_ * NL, 128, 0, stream>>>(adj, gw, wd);
  gcn_main_k<<<B / BB, TPB, 0, stream>>>(z, fc_w, fc_b, wd, gb, out);
}

// Round 4
// 179.833 us; speedup vs baseline: 3.3692x; 1.3264x over previous
//
#include <hip/hip_runtime.h>
#include <math.h>

// Problem constants
#define R_ 5
#define NN 68        // N_NODES == LATENT
#define KK 32        // neighbors per node
#define NL 3         // GCN layers
#define LAT 68
#define ROWQ (NN / 4)        // 17 float4 per node row
#define NF4 ((NN * NN) / 4)  // 1156 float4 per output row
#define BBK2 16              // batches per K2 block
#define LSTR 344             // LDS row stride (floats) for K2, 16B-aligned

// ---------------- P1: densify GCN weights ----------------
// W'[m][n] = sum_{k: adj[n,k]==m} gw[n,k]  (exact rewrite of the gather)
__global__ __launch_bounds__(128) void densify_k(
    const int* __restrict__ adj, const float* __restrict__ gw,
    float* __restrict__ wd) {
  const int rl = blockIdx.x;  // r*NL + l in 0..14
  const int t = threadIdx.x;
  __shared__ float col[NN][NN + 4];
  for (int i = t; i < NN * (NN + 4); i += 128) (&col[0][0])[i] = 0.0f;
  __syncthreads();
  if (t < NN) {
    const int n = t;  // thread owns column n -> no races
    const int* ar = adj + n * KK;
    const float* wr = gw + ((size_t)rl * NN + n) * KK;
    for (int k = 0; k < KK; ++k) col[ar[k]][n] += wr[k];
  }
  __syncthreads();
  float* wout = wd + (size_t)rl * NN * NN;  // [m][n], n contiguous
  for (int i = t; i < NN * NN; i += 128) {
    const int m = i / NN, n = i - m * NN;
    wout[i] = col[m][n];
  }
}

// ---------------- P2: transpose z -> zT[l][b] ----------------
__global__ __launch_bounds__(256) void ztr_k(const float* __restrict__ z,
                                             float* __restrict__ zT, int B) {
  const int t = threadIdx.x;
  const int b0 = blockIdx.x * 64;
  __shared__ float zls[64][LAT + 1];  // +1: stride 69 -> conflict-free both ways
  for (int idx = t; idx < 64 * ROWQ; idx += 256) {
    const int row = idx / ROWQ, q = idx - row * ROWQ;
    const float4 v =
        *reinterpret_cast<const float4*>(z + (size_t)(b0 + row) * LAT + 4 * q);
    zls[row][4 * q + 0] = v.x;
    zls[row][4 * q + 1] = v.y;
    zls[row][4 * q + 2] = v.z;
    zls[row][4 * q + 3] = v.w;
  }
  __syncthreads();
  for (int idx = t; idx < LAT * 64; idx += 256) {
    const int l = idx >> 6, bb = idx & 63;
    zT[(size_t)l * B + b0 + bb] = zls[bb][l];
  }
}

// ---------------- K1: GEMM-chain, single-wave blocks ----------------
// Block = 1 wave = (channel r, 64-batch group); lane = batch. x lives in a
// private 17.4 KB LDS slab [n][lane] (lane-private column, conflict-free).
// ~9 independent waves/CU, no inter-wave coupling, no load imbalance.
__global__ __launch_bounds__(64) void chain_k(
    const float* __restrict__ zT, const float* __restrict__ fc_w,
    const float* __restrict__ fc_b, const float* __restrict__ wd,
    const float* __restrict__ gb, float* __restrict__ X, int B, int nb) {
  const int lane = threadIdx.x;
  const int r = blockIdx.x / nb;        // blocks 0..nb-1 all r=0 -> L2-friendly
  const int b0 = (blockIdx.x - r * nb) * 64;

  __shared__ float xs[NN][64];
  float4 acc[ROWQ];  // 68 accumulators, statically indexed

  // ---- fc: x0 = z @ fc_w[r] + fc_b[r] ----
  {
    const float4* bi = reinterpret_cast<const float4*>(fc_b + r * NN);
#pragma unroll
    for (int j = 0; j < ROWQ; ++j) acc[j] = bi[j];
    const float* wb = fc_w + (size_t)r * LAT * NN;
#pragma unroll 2
    for (int m = 0; m < LAT; ++m) {
      const float xm = zT[(size_t)m * B + b0 + lane];  // coalesced 256B
      const float4* w4 = reinterpret_cast<const float4*>(wb + m * NN);
#pragma unroll
      for (int j = 0; j < ROWQ; ++j) {
        const float4 ww = w4[j];  // wave-uniform
        acc[j].x = fmaf(xm, ww.x, acc[j].x);
        acc[j].y = fmaf(xm, ww.y, acc[j].y);
        acc[j].z = fmaf(xm, ww.z, acc[j].z);
        acc[j].w = fmaf(xm, ww.w, acc[j].w);
      }
    }
#pragma unroll
    for (int j = 0; j < ROWQ; ++j) {
      xs[4 * j + 0][lane] = acc[j].x;
      xs[4 * j + 1][lane] = acc[j].y;
      xs[4 * j + 2][lane] = acc[j].z;
      xs[4 * j + 3][lane] = acc[j].w;
    }
    __syncthreads();  // 1-wave block: compiles to a cheap waitcnt
  }

  // ---- 3 GCN layers: x = sigmoid(x @ W'[r,l] + b) ----
  for (int l = 0; l < NL; ++l) {
    const float4* bi = reinterpret_cast<const float4*>(gb + (r * NL + l) * NN);
#pragma unroll
    for (int j = 0; j < ROWQ; ++j) acc[j] = bi[j];
    const float* wb = wd + (size_t)(r * NL + l) * NN * NN;
#pragma unroll 2
    for (int m = 0; m < NN; ++m) {
      const float xm = xs[m][lane];  // conflict-free (stride 64)
      const float4* w4 = reinterpret_cast<const float4*>(wb + m * NN);
#pragma unroll
      for (int j = 0; j < ROWQ; ++j) {
        const float4 ww = w4[j];
        acc[j].x = fmaf(xm, ww.x, acc[j].x);
        acc[j].y = fmaf(xm, ww.y, acc[j].y);
        acc[j].z = fmaf(xm, ww.z, acc[j].z);
        acc[j].w = fmaf(xm, ww.w, acc[j].w);
      }
    }
#pragma unroll
    for (int j = 0; j < ROWQ; ++j) {  // sigmoid
      acc[j].x = 1.0f / (1.0f + __expf(-acc[j].x));
      acc[j].y = 1.0f / (1.0f + __expf(-acc[j].y));
      acc[j].z = 1.0f / (1.0f + __expf(-acc[j].z));
      acc[j].w = 1.0f / (1.0f + __expf(-acc[j].w));
    }
    if (l < NL - 1) {
      __syncthreads();  // all reads of old xs done (values consumed)
#pragma unroll
      for (int j = 0; j < ROWQ; ++j) {
        xs[4 * j + 0][lane] = acc[j].x;
        xs[4 * j + 1][lane] = acc[j].y;
        xs[4 * j + 2][lane] = acc[j].z;
        xs[4 * j + 3][lane] = acc[j].w;
      }
      __syncthreads();
    }
  }

  // ---- X -> ws, layout [r*68+n][b]: 68 coalesced scalar stores ----
  float* Xb = X + (size_t)r * NN * B + b0 + lane;
#pragma unroll
  for (int j = 0; j < ROWQ; ++j) {
    Xb[(size_t)(4 * j + 0) * B] = acc[j].x;
    Xb[(size_t)(4 * j + 1) * B] = acc[j].y;
    Xb[(size_t)(4 * j + 2) * B] = acc[j].z;
    Xb[(size_t)(4 * j + 3) * B] = acc[j].w;
  }
}

// ---------------- K2: outer product + store (streaming) ----------------
// 16 batches/block, 22 KB LDS -> 7 blocks (28 waves)/CU. Stores are flat
// consecutive float4 across the wave (1 KB/instr).
__global__ __launch_bounds__(256) void outer_k(const float* __restrict__ X,
                                               float* __restrict__ out, int B) {
  const int t = threadIdx.x;
  const int b0 = blockIdx.x * BBK2;
  __shared__ float xls[BBK2 * LSTR];

  // stage X[rn][b0..b0+15] -> xls[bb][rn]; reads are exact 64B lines
  for (int idx = t; idx < R_ * NN * BBK2; idx += 256) {
    const int rn = idx >> 4, bb = idx & (BBK2 - 1);
    xls[bb * LSTR + rn] = X[(size_t)rn * B + b0 + bb];
  }
  __syncthreads();

  float4* ob = reinterpret_cast<float4*>(out) + (size_t)b0 * NF4;
  const int total = BBK2 * NF4;  // 18496
  for (int fg = t; fg < total; fg += 256) {
    const int bb = fg / NF4;
    const int f = fg - bb * NF4;
    const int i = f / ROWQ;
    const int q = f - i * ROWQ;
    const float* xb = &xls[bb * LSTR];
    float4 a = make_float4(0.f, 0.f, 0.f, 0.f);
#pragma unroll
    for (int r = 0; r < R_; ++r) {
      const float xi = xb[r * NN + i];
      const float4 xj = *reinterpret_cast<const float4*>(xb + r * NN + 4 * q);
      a.x = fmaf(xi, xj.x, a.x);
      a.y = fmaf(xi, xj.y, a.y);
      a.z = fmaf(xi, xj.z, a.z);
      a.w = fmaf(xi, xj.w, a.w);
    }
    ob[fg] = a;  // lanes consecutive -> perfectly coalesced
  }
}

extern "C" void kernel_launch(void* const* d_in, const int* in_sizes, int n_in,
                              void* d_out, int out_size, void* d_ws, size_t ws_size,
                              hipStream_t stream) {
  const float* z    = (const float*)d_in[0];  // (16384, 68)
  const int*   adj  = (const int*)  d_in[1];  // (68, 32)
  const float* fc_w = (const float*)d_in[2];  // (5, 68, 68)
  const float* fc_b = (const float*)d_in[3];  // (5, 68)
  const float* gw   = (const float*)d_in[4];  // (5, 3, 68, 32)
  const float* gb   = (const float*)d_in[5];  // (5, 3, 68)
  float* out = (float*)d_out;                 // (16384, 4624)

  const int B = in_sizes[0] / LAT;            // 16384
  // ws layout (f32): wd[15*68*68] | zT[68*B] | X[340*B]  (~27.1 MB total)
  float* wd = (float*)d_ws;
  float* zT = wd + R_ * NL * NN * NN;
  float* X  = zT + (size_t)LAT * B;

  const int nb = B / 64;                      // 256 batch-groups

  densify_k<<<R_ * NL, 128, 0, stream>>>(adj, gw, wd);
  ztr_k<<<B / 64, 256, 0, stream>>>(z, zT, B);
  chain_k<<<R_ * nb, 64, 0, stream>>>(zT, fc_w, fc_b, wd, gb, X, B, nb);
  outer_k<<<B / BBK2, 256, 0, stream>>>(X, out, B);
}